// Round 3
// baseline (444.974 us; speedup 1.0000x reference)
//
#include <hip/hip_runtime.h>
#include <math.h>

#define N_NODES 100000
#define N_EDGES 100000
#define NNZT    1600000
#define C       128
#define NB      ((N_NODES + 255) >> 8)    // 391 node-buckets of 256 nodes

typedef _Float16 half8 __attribute__((ext_vector_type(8)));
typedef _Float16 h2    __attribute__((ext_vector_type(2)));
typedef float    f32x4 __attribute__((ext_vector_type(4)));
typedef int      i2v   __attribute__((ext_vector_type(2)));

// K1: t_node[i] = dot(x_0[i], a_tgt); also emit x0h = (fp16)x0.
// One wave per node row (64 lanes x float2), no LDS, no barriers.
__global__ __launch_bounds__(256) void k1_node_dot(
    const float* __restrict__ x0, const float* __restrict__ att,
    float* __restrict__ t_node, _Float16* __restrict__ x0h)
{
    int wave = threadIdx.x >> 6;
    int lane = threadIdx.x & 63;
    int node = blockIdx.x * 4 + wave;          // 100000 % 4 == 0
    const float2 xv = *reinterpret_cast<const float2*>(x0 + (size_t)node * C + lane * 2);
    h2 hx = { (_Float16)xv.x, (_Float16)xv.y };
    *reinterpret_cast<h2*>(x0h + (size_t)node * C + lane * 2) = hx;
    const float2 av = *reinterpret_cast<const float2*>(att + C + lane * 2);
    float v = xv.x * av.x + xv.y * av.y;
    #pragma unroll
    for (int off = 32; off > 0; off >>= 1) v += __shfl_xor(v, off, 64);
    if (lane == 0) t_node[node] = v;
}

// RP: edge row pointer from sorted edge_idx, atomic-free one pass.
__global__ __launch_bounds__(256) void k_rowptr(
    const int* __restrict__ edge_idx, int* __restrict__ row_start)
{
    int e = blockIdx.x * 256 + threadIdx.x;
    if (e >= NNZT) return;
    int j = edge_idx[e];
    int jprev = (e == 0) ? -1 : edge_idx[e - 1];
    for (int k = jprev + 1; k <= j; ++k) row_start[k] = e;
    if (e == NNZT - 1)
        for (int k = j + 1; k <= N_EDGES; ++k) row_start[k] = NNZT;
}

// WC: Wt[n][k] = (fp16) W[k][n]  (transposed fp16 weight for MFMA B-frags)
__global__ __launch_bounds__(256) void k_wcvt(
    const float* __restrict__ W, _Float16* __restrict__ wt)
{
    int i = blockIdx.x * 256 + threadIdx.x;   // 16384
    int k = i >> 7, n = i & 127;
    wt[(size_t)n * C + k] = (_Float16)W[(size_t)k * C + n];
}

// K2: segment sum -> m01h row (fp16) + s_edge dot, via row_start.
// ONE WAVE PER ROW: 4 edge-slots x 16 lanes x half8, MLP=4 unroll,
// nontemporal loads on the read-once idx/value streams.
__global__ __launch_bounds__(256) void k2_edge_msg(
    const half8* __restrict__ x0h,
    const int*   __restrict__ node_idx,
    const int*   __restrict__ row_start,
    const float* __restrict__ values,
    const float* __restrict__ att,
    _Float16* __restrict__ m01h,
    float* __restrict__ s_edge)
{
    int wave = threadIdx.x >> 6;
    int lane = threadIdx.x & 63;
    int j    = blockIdx.x * 4 + wave;          // 100000 % 4 == 0
    int sub  = lane >> 4;                      // 0..3 edge slot
    int ln   = lane & 15;                      // half8 chunk of the row
    int start = row_start[j];
    int end   = row_start[j + 1];

    h2 hacc[4];
    #pragma unroll
    for (int q = 0; q < 4; ++q) hacc[q] = (h2){(_Float16)0.f, (_Float16)0.f};

    int e = start + sub;
    for (; e + 12 < end; e += 16) {
        int n0 = __builtin_nontemporal_load(node_idx + e);
        int n1 = __builtin_nontemporal_load(node_idx + e + 4);
        int n2 = __builtin_nontemporal_load(node_idx + e + 8);
        int n3 = __builtin_nontemporal_load(node_idx + e + 12);
        float f0 = __builtin_nontemporal_load(values + e);
        float f1 = __builtin_nontemporal_load(values + e + 4);
        float f2 = __builtin_nontemporal_load(values + e + 8);
        float f3 = __builtin_nontemporal_load(values + e + 12);
        half8 A = x0h[(size_t)n0 * 16 + ln];
        half8 B = x0h[(size_t)n1 * 16 + ln];
        half8 Cg = x0h[(size_t)n2 * 16 + ln];
        half8 D = x0h[(size_t)n3 * 16 + ln];
        _Float16 v0 = (_Float16)f0, v1 = (_Float16)f1;
        _Float16 v2 = (_Float16)f2, v3 = (_Float16)f3;
        h2 v0p = {v0, v0}, v1p = {v1, v1}, v2p = {v2, v2}, v3p = {v3, v3};
        const h2* a2 = reinterpret_cast<const h2*>(&A);
        const h2* b2 = reinterpret_cast<const h2*>(&B);
        const h2* c2 = reinterpret_cast<const h2*>(&Cg);
        const h2* d2 = reinterpret_cast<const h2*>(&D);
        #pragma unroll
        for (int q = 0; q < 4; ++q)
            hacc[q] = a2[q] * v0p
                    + (b2[q] * v1p + (c2[q] * v2p + (d2[q] * v3p + hacc[q])));
    }
    for (; e + 4 < end; e += 8) {
        int n0 = __builtin_nontemporal_load(node_idx + e);
        int n1 = __builtin_nontemporal_load(node_idx + e + 4);
        float f0 = __builtin_nontemporal_load(values + e);
        float f1 = __builtin_nontemporal_load(values + e + 4);
        half8 A = x0h[(size_t)n0 * 16 + ln];
        half8 B = x0h[(size_t)n1 * 16 + ln];
        _Float16 v0 = (_Float16)f0, v1 = (_Float16)f1;
        h2 v0p = {v0, v0}, v1p = {v1, v1};
        const h2* a2 = reinterpret_cast<const h2*>(&A);
        const h2* b2 = reinterpret_cast<const h2*>(&B);
        #pragma unroll
        for (int q = 0; q < 4; ++q)
            hacc[q] = a2[q] * v0p + (b2[q] * v1p + hacc[q]);
    }
    if (e < end) {
        int n0 = __builtin_nontemporal_load(node_idx + e);
        float f0 = __builtin_nontemporal_load(values + e);
        _Float16 v0 = (_Float16)f0;
        h2 v0p = {v0, v0};
        half8 A = x0h[(size_t)n0 * 16 + ln];
        const h2* a2 = reinterpret_cast<const h2*>(&A);
        #pragma unroll
        for (int q = 0; q < 4; ++q) hacc[q] = a2[q] * v0p + hacc[q];
    }

    // f32 cross-slot reduction, all in-wave.
    float f[8];
    #pragma unroll
    for (int q = 0; q < 4; ++q) {
        f[2 * q]     = (float)hacc[q][0];
        f[2 * q + 1] = (float)hacc[q][1];
    }
    #pragma unroll
    for (int q = 0; q < 8; ++q) {
        f[q] += __shfl_xor(f[q], 16, 64);
        f[q] += __shfl_xor(f[q], 32, 64);
    }
    if (lane < 16) {
        half8 hv;
        #pragma unroll
        for (int q = 0; q < 8; ++q) hv[q] = (_Float16)f[q];
        reinterpret_cast<half8*>(m01h + (size_t)j * C)[ln] = hv;
    }
    // s_edge[j] = dot(m01 row, a_src)
    f32x4 a0 = *reinterpret_cast<const f32x4*>(att + ln * 8);
    f32x4 a1 = *reinterpret_cast<const f32x4*>(att + ln * 8 + 4);
    float p = f[0] * a0[0] + f[1] * a0[1] + f[2] * a0[2] + f[3] * a0[3]
            + f[4] * a1[0] + f[5] * a1[1] + f[6] * a1[2] + f[7] * a1[3];
    #pragma unroll
    for (int off = 8; off > 0; off >>= 1) p += __shfl_xor(p, off, 64);
    if (lane == 0) s_edge[j] = p;
}

// H: per-node histogram via global atomics (count is 400KB, L2-resident;
// avg 16 hits/counter -> negligible contention). Full 6250-block grid.
__global__ __launch_bounds__(256) void k_hist(
    const int* __restrict__ node_idx, int* __restrict__ count)
{
    int e = blockIdx.x * 256 + threadIdx.x;
    if (e < NNZT) atomicAdd(&count[node_idx[e]], 1);
}

// BT: btot[b] = sum of count over bucket b (LDS tree reduce).
__global__ __launch_bounds__(256) void k_btot(
    const int* __restrict__ count, int* __restrict__ btot)
{
    __shared__ int s[256];
    int b = blockIdx.x, tid = threadIdx.x;
    int nn = (b << 8) + tid;
    s[tid] = (nn < N_NODES) ? count[nn] : 0;
    __syncthreads();
    #pragma unroll
    for (int off = 128; off > 0; off >>= 1) {
        if (tid < off) s[tid] += s[tid + off];
        __syncthreads();
    }
    if (tid == 0) btot[b] = s[0];
}

// BS: exclusive scan of 391 bucket totals -> bbase[0..NB].
__global__ __launch_bounds__(512) void k_bscan(
    const int* __restrict__ btot, int* __restrict__ bbase)
{
    __shared__ int s[512];
    int tid = threadIdx.x;
    int v = (tid < NB) ? btot[tid] : 0;
    s[tid] = v;
    __syncthreads();
    for (int off = 1; off < 512; off <<= 1) {
        int t = (tid >= off) ? s[tid - off] : 0;
        __syncthreads();
        s[tid] += t;
        __syncthreads();
    }
    if (tid < NB) bbase[tid] = s[tid] - v;
    if (tid == NB - 1) bbase[NB] = s[tid];
}

// NBASE: per-node base = bbase[bucket] + within-bucket exclusive scan;
// cur initialized to base for the scatter.
__global__ __launch_bounds__(256) void k_nbase(
    const int* __restrict__ count, const int* __restrict__ bbase,
    int* __restrict__ base, int* __restrict__ cur)
{
    int b = blockIdx.x, tid = threadIdx.x;
    int nn = (b << 8) + tid;
    __shared__ int scn[256];
    int v = (nn < N_NODES) ? count[nn] : 0;
    scn[tid] = v;
    __syncthreads();
    for (int off = 1; off < 256; off <<= 1) {
        int t = (tid >= off) ? scn[tid - off] : 0;
        __syncthreads();
        scn[tid] += t;
        __syncthreads();
    }
    int excl = scn[tid] - v;
    if (nn < N_NODES) {
        int bs = bbase[b] + excl;
        base[nn] = bs;
        cur[nn]  = bs;
    }
}

// SC: direct counting-sort scatter. One pass: compute coef, reserve slot
// via atomicAdd on per-node cursor (L2-resident), single 8B store.
// s_edge reads are near-sequential (edge_idx sorted); t_node is an
// L2-resident 400KB gather.
__global__ __launch_bounds__(256) void k_scatter(
    const int*   __restrict__ node_idx,
    const int*   __restrict__ edge_idx,
    const float* __restrict__ values,
    const float* __restrict__ s_edge,
    const float* __restrict__ t_node,
    int*  __restrict__ cur,
    int2* __restrict__ jc)
{
    int e = blockIdx.x * 256 + threadIdx.x;
    if (e >= NNZT) return;
    int n = __builtin_nontemporal_load(node_idx + e);
    int j = __builtin_nontemporal_load(edge_idx + e);
    float vv = __builtin_nontemporal_load(values + e);
    float s = s_edge[j] + t_node[n];
    float coef = (s > 0.f ? s : expm1f(s)) * vv;
    int pos = atomicAdd(&cur[n], 1);
    jc[pos] = make_int2(j, __float_as_int(coef));
}

// K3: gather-accumulate per destination node (atomic-free), fp16 rows.
// ONE WAVE PER NODE: 4 slots x 16 lanes x half8, MLP=4 unroll.
__global__ __launch_bounds__(256) void k3_gather(
    const half8* __restrict__ m01h,
    const int2*  __restrict__ jc,
    const int*   __restrict__ base,
    const int*   __restrict__ count,
    _Float16* __restrict__ yh)
{
    int wave = threadIdx.x >> 6;
    int lane = threadIdx.x & 63;
    int n    = blockIdx.x * 4 + wave;          // 100000 % 4 == 0
    int sub  = lane >> 4;
    int ln   = lane & 15;
    int b    = base[n];
    int cnt  = count[n];
    const i2v* jcv = reinterpret_cast<const i2v*>(jc);

    float facc[8];
    #pragma unroll
    for (int q = 0; q < 8; ++q) facc[q] = 0.f;

    int i = sub;
    for (; i + 12 < cnt; i += 16) {
        i2v p0 = __builtin_nontemporal_load(jcv + b + i);
        i2v p1 = __builtin_nontemporal_load(jcv + b + i + 4);
        i2v p2 = __builtin_nontemporal_load(jcv + b + i + 8);
        i2v p3 = __builtin_nontemporal_load(jcv + b + i + 12);
        half8 a0 = m01h[(size_t)p0[0] * 16 + ln];
        half8 a1 = m01h[(size_t)p1[0] * 16 + ln];
        half8 a2 = m01h[(size_t)p2[0] * 16 + ln];
        half8 a3 = m01h[(size_t)p3[0] * 16 + ln];
        float c0 = __int_as_float(p0[1]);
        float c1 = __int_as_float(p1[1]);
        float c2 = __int_as_float(p2[1]);
        float c3 = __int_as_float(p3[1]);
        #pragma unroll
        for (int q = 0; q < 8; ++q)
            facc[q] += c0 * (float)a0[q] + c1 * (float)a1[q]
                     + c2 * (float)a2[q] + c3 * (float)a3[q];
    }
    for (; i + 4 < cnt; i += 8) {
        i2v p0 = __builtin_nontemporal_load(jcv + b + i);
        i2v p1 = __builtin_nontemporal_load(jcv + b + i + 4);
        half8 a0 = m01h[(size_t)p0[0] * 16 + ln];
        half8 a1 = m01h[(size_t)p1[0] * 16 + ln];
        float c0 = __int_as_float(p0[1]);
        float c1 = __int_as_float(p1[1]);
        #pragma unroll
        for (int q = 0; q < 8; ++q)
            facc[q] += c0 * (float)a0[q] + c1 * (float)a1[q];
    }
    if (i < cnt) {
        i2v p0 = __builtin_nontemporal_load(jcv + b + i);
        float c0 = __int_as_float(p0[1]);
        half8 a0 = m01h[(size_t)p0[0] * 16 + ln];
        #pragma unroll
        for (int q = 0; q < 8; ++q) facc[q] += c0 * (float)a0[q];
    }

    #pragma unroll
    for (int q = 0; q < 8; ++q) {
        facc[q] += __shfl_xor(facc[q], 16, 64);
        facc[q] += __shfl_xor(facc[q], 32, 64);
    }
    if (lane < 16) {
        half8 hv;
        #pragma unroll
        for (int q = 0; q < 8; ++q) hv[q] = (_Float16)facc[q];
        reinterpret_cast<half8*>(yh + (size_t)n * C)[ln] = hv;
    }
}

// K4: out = yh @ W via MFMA f16. One wave per 16 rows; 8 col-tiles x 4 k-chunks.
__global__ __launch_bounds__(64) void k4_mfma(
    const _Float16* __restrict__ yh,   // N_NODES x C row-major
    const _Float16* __restrict__ wt,   // wt[n*C+k] = W[k][n]
    float* __restrict__ out)
{
    int lane = threadIdx.x;            // 0..63
    int m    = lane & 15;
    int quad = lane >> 4;              // 0..3
    int rb   = blockIdx.x * 16;
    const _Float16* yrow = yh + (size_t)(rb + m) * C + quad * 8;
    half8 a[4];
    #pragma unroll
    for (int kc = 0; kc < 4; ++kc)
        a[kc] = *reinterpret_cast<const half8*>(yrow + kc * 32);
    #pragma unroll
    for (int ct = 0; ct < 8; ++ct) {
        const _Float16* wrow = wt + (size_t)(ct * 16 + m) * C + quad * 8;
        f32x4 acc = {0.f, 0.f, 0.f, 0.f};
        #pragma unroll
        for (int kc = 0; kc < 4; ++kc) {
            half8 b = *reinterpret_cast<const half8*>(wrow + kc * 32);
            acc = __builtin_amdgcn_mfma_f32_16x16x32_f16(a[kc], b, acc, 0, 0, 0);
        }
        int orow = rb + quad * 4;
        int ocol = ct * 16 + m;
        #pragma unroll
        for (int r = 0; r < 4; ++r)
            out[(size_t)(orow + r) * C + ocol] = acc[r];
    }
}

extern "C" void kernel_launch(void* const* d_in, const int* in_sizes, int n_in,
                              void* d_out, int out_size, void* d_ws, size_t ws_size,
                              hipStream_t stream)
{
    const float* x0       = (const float*)d_in[0];
    const int*   node_idx = (const int*)  d_in[1];
    const int*   edge_idx = (const int*)  d_in[2];
    const float* values   = (const float*)d_in[3];
    const float* W        = (const float*)d_in[4];
    const float* att      = (const float*)d_in[5];
    float* out = (float*)d_out;

    // d_out layout: [x0h 25.6MB][m01h 25.6MB]. Both dead before k4 writes out.
    _Float16* x0h_s  = (_Float16*)d_out;
    _Float16* m01h_s = x0h_s + (size_t)N_NODES * C;

    char*  p   = (char*)d_ws;
    _Float16* yh    = (_Float16*)p; p += (size_t)N_NODES * C * sizeof(_Float16); // 25.6 MB
    float* t_node   = (float*)p;  p += N_NODES * sizeof(float);
    float* s_edge   = (float*)p;  p += N_EDGES * sizeof(float);
    int*   count    = (int*)p;    p += N_NODES * sizeof(int);
    int*   base     = (int*)p;    p += N_NODES * sizeof(int);
    int*   cur      = (int*)p;    p += N_NODES * sizeof(int);
    int*   btot     = (int*)p;    p += 512 * sizeof(int);
    int*   bbase    = (int*)p;    p += 512 * sizeof(int);
    int*   row_start= (int*)p;    p += (N_EDGES + 1) * sizeof(int);
    _Float16* wt    = (_Float16*)p; p += (size_t)C * C * sizeof(_Float16);       // 32 KB
    int2*  jc       = (int2*)p;   p += (size_t)NNZT * sizeof(int2);              // 12.8 MB

    hipMemsetAsync(count, 0, N_NODES * sizeof(int), stream);

    k1_node_dot<<<N_NODES / 4, 256, 0, stream>>>(x0, att, t_node, x0h_s);
    k_rowptr<<<(NNZT + 255) / 256, 256, 0, stream>>>(edge_idx, row_start);
    k_wcvt  <<<(C * C + 255) / 256, 256, 0, stream>>>(W, wt);
    k2_edge_msg<<<N_EDGES / 4, 256, 0, stream>>>((const half8*)x0h_s, node_idx, row_start,
                                                 values, att, m01h_s, s_edge);

    k_hist <<<(NNZT + 255) / 256, 256, 0, stream>>>(node_idx, count);
    k_btot <<<NB, 256, 0, stream>>>(count, btot);
    k_bscan<<<1, 512, 0, stream>>>(btot, bbase);
    k_nbase<<<NB, 256, 0, stream>>>(count, bbase, base, cur);
    k_scatter<<<(NNZT + 255) / 256, 256, 0, stream>>>(node_idx, edge_idx, values,
                                                      s_edge, t_node, cur, jc);

    k3_gather<<<N_NODES / 4, 256, 0, stream>>>((const half8*)m01h_s, jc, base, count, yh);
    k4_mfma<<<N_NODES / 16, 64, 0, stream>>>(yh, wt, out);
}

// Round 4
// 358.298 us; speedup vs baseline: 1.2419x; 1.2419x over previous
//
#include <hip/hip_runtime.h>
#include <math.h>

#define N_NODES 100000
#define N_EDGES 100000
#define NNZT    1600000
#define C       128
#define NB      ((N_NODES + 255) >> 8)    // 391 node-buckets of 256 nodes
#define CHUNK   4096                      // edges per k_part block
#define ORDCAP  6144                      // per-bucket sort capacity (mean 4096, sigma~64)

typedef _Float16 half8 __attribute__((ext_vector_type(8)));
typedef _Float16 h2    __attribute__((ext_vector_type(2)));
typedef float    f32x4 __attribute__((ext_vector_type(4)));

// K1: t_node[i] = dot(x_0[i], a_tgt); also emit x0h = (fp16)x0.
// One wave per node row (64 lanes x float2), no LDS, no barriers.
__global__ __launch_bounds__(256) void k1_node_dot(
    const float* __restrict__ x0, const float* __restrict__ att,
    float* __restrict__ t_node, _Float16* __restrict__ x0h)
{
    int wave = threadIdx.x >> 6;
    int lane = threadIdx.x & 63;
    int node = blockIdx.x * 4 + wave;          // 100000 % 4 == 0
    const float2 xv = *reinterpret_cast<const float2*>(x0 + (size_t)node * C + lane * 2);
    h2 hx = { (_Float16)xv.x, (_Float16)xv.y };
    *reinterpret_cast<h2*>(x0h + (size_t)node * C + lane * 2) = hx;
    const float2 av = *reinterpret_cast<const float2*>(att + C + lane * 2);
    float v = xv.x * av.x + xv.y * av.y;
    #pragma unroll
    for (int off = 32; off > 0; off >>= 1) v += __shfl_xor(v, off, 64);
    if (lane == 0) t_node[node] = v;
}

// RP: edge row pointer from sorted edge_idx, atomic-free one pass.
__global__ __launch_bounds__(256) void k_rowptr(
    const int* __restrict__ edge_idx, int* __restrict__ row_start)
{
    int e = blockIdx.x * 256 + threadIdx.x;
    if (e >= NNZT) return;
    int j = edge_idx[e];
    int jprev = (e == 0) ? -1 : edge_idx[e - 1];
    for (int k = jprev + 1; k <= j; ++k) row_start[k] = e;
    if (e == NNZT - 1)
        for (int k = j + 1; k <= N_EDGES; ++k) row_start[k] = NNZT;
}

// WC: Wt[n][k] = (fp16) W[k][n]  (transposed fp16 weight for MFMA B-frags)
__global__ __launch_bounds__(256) void k_wcvt(
    const float* __restrict__ W, _Float16* __restrict__ wt)
{
    int i = blockIdx.x * 256 + threadIdx.x;   // 16384
    int k = i >> 7, n = i & 127;
    wt[(size_t)n * C + k] = (_Float16)W[(size_t)k * C + n];
}

// K2: segment sum -> m01h row (fp16) + s_edge dot, via row_start.
// ONE WAVE PER ROW: 4 edge-slots x 16 lanes x half8; shfl_xor cross-slot
// reduce; no LDS, no barriers. (Round-1 body, measured 67us. NO nontemporal
// hints: node_idx/values are re-read by later kernels and must stay in L2.)
__global__ __launch_bounds__(256) void k2_edge_msg(
    const half8* __restrict__ x0h,
    const int*   __restrict__ node_idx,
    const int*   __restrict__ row_start,
    const float* __restrict__ values,
    const float* __restrict__ att,
    _Float16* __restrict__ m01h,
    float* __restrict__ s_edge)
{
    int wave = threadIdx.x >> 6;
    int lane = threadIdx.x & 63;
    int j    = blockIdx.x * 4 + wave;          // 100000 % 4 == 0
    int sub  = lane >> 4;                      // 0..3 edge slot
    int ln   = lane & 15;                      // half8 chunk of the row
    int start = row_start[j];
    int end   = row_start[j + 1];

    h2 hacc[4];
    #pragma unroll
    for (int q = 0; q < 4; ++q) hacc[q] = (h2){(_Float16)0.f, (_Float16)0.f};

    int e = start + sub;
    for (; e + 4 < end; e += 8) {
        int   n0 = node_idx[e];
        int   n1 = node_idx[e + 4];
        _Float16 v0 = (_Float16)values[e];
        _Float16 v1 = (_Float16)values[e + 4];
        h2 v0p = {v0, v0}, v1p = {v1, v1};
        half8 A = x0h[(size_t)n0 * 16 + ln];
        half8 B = x0h[(size_t)n1 * 16 + ln];
        const h2* a2 = reinterpret_cast<const h2*>(&A);
        const h2* b2 = reinterpret_cast<const h2*>(&B);
        #pragma unroll
        for (int q = 0; q < 4; ++q)
            hacc[q] = a2[q] * v0p + (b2[q] * v1p + hacc[q]);
    }
    if (e < end) {
        int   n0 = node_idx[e];
        _Float16 v0 = (_Float16)values[e];
        h2 v0p = {v0, v0};
        half8 A = x0h[(size_t)n0 * 16 + ln];
        const h2* a2 = reinterpret_cast<const h2*>(&A);
        #pragma unroll
        for (int q = 0; q < 4; ++q) hacc[q] = a2[q] * v0p + hacc[q];
    }

    // f32 cross-slot reduction, all in-wave.
    float f[8];
    #pragma unroll
    for (int q = 0; q < 4; ++q) {
        f[2 * q]     = (float)hacc[q][0];
        f[2 * q + 1] = (float)hacc[q][1];
    }
    #pragma unroll
    for (int q = 0; q < 8; ++q) {
        f[q] += __shfl_xor(f[q], 16, 64);
        f[q] += __shfl_xor(f[q], 32, 64);
    }
    if (lane < 16) {
        half8 hv;
        #pragma unroll
        for (int q = 0; q < 8; ++q) hv[q] = (_Float16)f[q];
        reinterpret_cast<half8*>(m01h + (size_t)j * C)[ln] = hv;
    }
    // s_edge[j] = dot(m01 row, a_src)
    f32x4 a0 = *reinterpret_cast<const f32x4*>(att + ln * 8);
    f32x4 a1 = *reinterpret_cast<const f32x4*>(att + ln * 8 + 4);
    float p = f[0] * a0[0] + f[1] * a0[1] + f[2] * a0[2] + f[3] * a0[3]
            + f[4] * a1[0] + f[5] * a1[1] + f[6] * a1[2] + f[7] * a1[3];
    #pragma unroll
    for (int off = 8; off > 0; off >>= 1) p += __shfl_xor(p, off, 64);
    if (lane == 0) s_edge[j] = p;
}

// BH: per-bucket totals. Wave-private LDS histograms -> ~100k global adds.
__global__ __launch_bounds__(256) void k_bhist(
    const int* __restrict__ node_idx, int* __restrict__ btot)
{
    __shared__ int cnt4[4][NB];
    int tid = threadIdx.x;
    int w   = tid >> 6;
    for (int b = tid; b < 4 * NB; b += 256) (&cnt4[0][0])[b] = 0;
    __syncthreads();
    const int per = (NNZT + 255) / 256;   // 6250
    int e0 = blockIdx.x * per;
    int e1 = e0 + per; if (e1 > NNZT) e1 = NNZT;
    for (int e = e0 + tid; e < e1; e += 256)
        atomicAdd(&cnt4[w][node_idx[e] >> 8], 1);
    __syncthreads();
    for (int b = tid; b < NB; b += 256) {
        int cc = cnt4[0][b] + cnt4[1][b] + cnt4[2][b] + cnt4[3][b];
        if (cc) atomicAdd(&btot[b], cc);
    }
}

// BS: exclusive scan of 391 bucket totals -> bbase[0..NB], bcur init.
__global__ __launch_bounds__(512) void k_bscan(
    const int* __restrict__ btot, int* __restrict__ bbase, int* __restrict__ bcur)
{
    __shared__ int s[512];
    int tid = threadIdx.x;
    int v = (tid < NB) ? btot[tid] : 0;
    s[tid] = v;
    __syncthreads();
    for (int off = 1; off < 512; off <<= 1) {
        int t = (tid >= off) ? s[tid - off] : 0;
        __syncthreads();
        s[tid] += t;
        __syncthreads();
    }
    if (tid < NB) { bbase[tid] = s[tid] - v; bcur[tid] = s[tid] - v; }
    if (tid == NB - 1) bbase[NB] = s[tid];
}

// PART: LDS counting-sort partition. Each block sorts CHUNK edges by bucket
// (n>>8) entirely in LDS, reserves per-bucket global slabs, then flushes
// bucket-contiguous runs with CONSECUTIVE THREADS -> each 64B line is fully
// written within one wave-store (temporal density), killing the RMW
// write-amplification the direct scatter suffered (113MB for a 12.8MB payload).
// Record: {(n&255)<<17 | j, coef} -- 8B, j<2^17, local node in bits 17..24.
__global__ __launch_bounds__(512) void k_part(
    const int*   __restrict__ node_idx,
    const int*   __restrict__ edge_idx,
    const float* __restrict__ values,
    const float* __restrict__ s_edge,
    const float* __restrict__ t_node,
    int*  __restrict__ bcur,
    int2* __restrict__ rec)
{
    __shared__ int hist[NB];          // counts -> inclusive scan
    __shared__ int lbase[NB];         // exclusive (local slab base)
    __shared__ int gb[NB];            // global slab base
    __shared__ int cur[NB];           // local write cursor
    __shared__ int2 lrec[CHUNK];                  // 32 KB
    __shared__ unsigned short lbid[CHUNK];        // 8 KB
    int tid = threadIdx.x;
    int e0 = blockIdx.x * CHUNK;
    int m = NNZT - e0; if (m > CHUNK) m = CHUNK;

    for (int b = tid; b < NB; b += 512) hist[b] = 0;
    __syncthreads();
    for (int i = tid; i < m; i += 512)
        atomicAdd(&hist[node_idx[e0 + i] >> 8], 1);
    __syncthreads();
    int c = (tid < NB) ? hist[tid] : 0;
    for (int off = 1; off < NB; off <<= 1) {
        int t = 0;
        if (tid < NB && tid >= off) t = hist[tid - off];
        __syncthreads();
        if (tid < NB) hist[tid] += t;
        __syncthreads();
    }
    if (tid < NB) {
        int excl = hist[tid] - c;
        lbase[tid] = excl;
        cur[tid]   = excl;
        gb[tid]    = c ? atomicAdd(&bcur[tid], c) : 0;
    }
    __syncthreads();
    // LDS scatter into bucket-sorted order (inputs L1-hot from pass 1)
    for (int i = tid; i < m; i += 512) {
        int e = e0 + i;
        int n = node_idx[e];
        int b = n >> 8;
        int j = edge_idx[e];
        float v = values[e];
        float s = s_edge[j] + t_node[n];
        float coef = (s > 0.f ? s : expm1f(s)) * v;
        int slot = atomicAdd(&cur[b], 1);
        lrec[slot] = make_int2(((n & 255) << 17) | j, __float_as_int(coef));
        lbid[slot] = (unsigned short)b;
    }
    __syncthreads();
    // coalesced flush: consecutive threads -> consecutive global addresses
    for (int s = tid; s < m; s += 512) {
        int b = lbid[s];
        rec[gb[b] + (s - lbase[b])] = lrec[s];
    }
}

// BG: fused binB + k3. One block per bucket: read the bucket's record slab
// (~32KB, sequential, stays L1/L2-hot), index-sort by local node in LDS,
// then wave-per-node gather-accumulate from m01h straight into yh.
// Eliminates the jc write+read round-trip entirely.
__global__ __launch_bounds__(512) void k_bgather(
    const int2*  __restrict__ rec,
    const int*   __restrict__ bbase,
    const half8* __restrict__ m01h,
    _Float16* __restrict__ yh)
{
    __shared__ int cnt[256];
    __shared__ int bl[256];           // inclusive scan of cnt
    __shared__ int cur[256];
    __shared__ unsigned short ord[ORDCAP];   // 12 KB
    int b = blockIdx.x, tid = threadIdx.x;
    int lo = bbase[b], hi = bbase[b + 1];
    int m = hi - lo;
    int mm = m < ORDCAP ? m : ORDCAP;

    if (tid < 256) cnt[tid] = 0;
    __syncthreads();
    for (int i = tid; i < mm; i += 512)
        atomicAdd(&cnt[((unsigned)rec[lo + i].x) >> 17], 1);
    __syncthreads();
    if (tid < 256) bl[tid] = cnt[tid];
    __syncthreads();
    for (int off = 1; off < 256; off <<= 1) {
        int t = 0;
        if (tid < 256 && tid >= off) t = bl[tid - off];
        __syncthreads();
        if (tid < 256) bl[tid] += t;
        __syncthreads();
    }
    if (tid < 256) cur[tid] = bl[tid] - cnt[tid];
    __syncthreads();
    for (int i = tid; i < mm; i += 512) {
        int local = ((unsigned)rec[lo + i].x) >> 17;
        int p = atomicAdd(&cur[local], 1);
        ord[p] = (unsigned short)i;
    }
    __syncthreads();

    int wave = tid >> 6, lane = tid & 63, sub = lane >> 4, ln = lane & 15;
    for (int local = wave; local < 256; local += 8) {
        int n = (b << 8) + local;
        if (n >= N_NODES) break;
        int cb = bl[local] - cnt[local];
        int cc = cnt[local];
        float facc[8];
        #pragma unroll
        for (int q = 0; q < 8; ++q) facc[q] = 0.f;
        int i = sub;
        for (; i + 4 < cc; i += 8) {
            int2 r0 = rec[lo + ord[cb + i]];
            int2 r1 = rec[lo + ord[cb + i + 4]];
            half8 a0 = m01h[(size_t)(r0.x & 0x1FFFF) * 16 + ln];
            half8 a1 = m01h[(size_t)(r1.x & 0x1FFFF) * 16 + ln];
            float c0 = __int_as_float(r0.y);
            float c1 = __int_as_float(r1.y);
            #pragma unroll
            for (int q = 0; q < 8; ++q)
                facc[q] += c0 * (float)a0[q] + c1 * (float)a1[q];
        }
        if (i < cc) {
            int2 r0 = rec[lo + ord[cb + i]];
            half8 a0 = m01h[(size_t)(r0.x & 0x1FFFF) * 16 + ln];
            float c0 = __int_as_float(r0.y);
            #pragma unroll
            for (int q = 0; q < 8; ++q) facc[q] += c0 * (float)a0[q];
        }
        // overflow fallback (m > ORDCAP): linear scan of unsorted tail.
        // Practically never taken (bucket mean 4096, sigma~64, cap 6144).
        for (int x = ORDCAP + sub; x < m; x += 4) {
            int2 r = rec[lo + x];
            if ((int)(((unsigned)r.x) >> 17) == local) {
                float c0 = __int_as_float(r.y);
                half8 a0 = m01h[(size_t)(r.x & 0x1FFFF) * 16 + ln];
                #pragma unroll
                for (int q = 0; q < 8; ++q) facc[q] += c0 * (float)a0[q];
            }
        }
        #pragma unroll
        for (int q = 0; q < 8; ++q) {
            facc[q] += __shfl_xor(facc[q], 16, 64);
            facc[q] += __shfl_xor(facc[q], 32, 64);
        }
        if (lane < 16) {
            half8 hv;
            #pragma unroll
            for (int q = 0; q < 8; ++q) hv[q] = (_Float16)facc[q];
            reinterpret_cast<half8*>(yh + (size_t)n * C)[ln] = hv;
        }
    }
}

// K4: out = yh @ W via MFMA f16. One wave per 16 rows; 8 col-tiles x 4 k-chunks.
__global__ __launch_bounds__(64) void k4_mfma(
    const _Float16* __restrict__ yh,   // N_NODES x C row-major
    const _Float16* __restrict__ wt,   // wt[n*C+k] = W[k][n]
    float* __restrict__ out)
{
    int lane = threadIdx.x;            // 0..63
    int m    = lane & 15;
    int quad = lane >> 4;              // 0..3
    int rb   = blockIdx.x * 16;
    const _Float16* yrow = yh + (size_t)(rb + m) * C + quad * 8;
    half8 a[4];
    #pragma unroll
    for (int kc = 0; kc < 4; ++kc)
        a[kc] = *reinterpret_cast<const half8*>(yrow + kc * 32);
    #pragma unroll
    for (int ct = 0; ct < 8; ++ct) {
        const _Float16* wrow = wt + (size_t)(ct * 16 + m) * C + quad * 8;
        f32x4 acc = {0.f, 0.f, 0.f, 0.f};
        #pragma unroll
        for (int kc = 0; kc < 4; ++kc) {
            half8 b = *reinterpret_cast<const half8*>(wrow + kc * 32);
            acc = __builtin_amdgcn_mfma_f32_16x16x32_f16(a[kc], b, acc, 0, 0, 0);
        }
        int orow = rb + quad * 4;
        int ocol = ct * 16 + m;
        #pragma unroll
        for (int r = 0; r < 4; ++r)
            out[(size_t)(orow + r) * C + ocol] = acc[r];
    }
}

extern "C" void kernel_launch(void* const* d_in, const int* in_sizes, int n_in,
                              void* d_out, int out_size, void* d_ws, size_t ws_size,
                              hipStream_t stream)
{
    const float* x0       = (const float*)d_in[0];
    const int*   node_idx = (const int*)  d_in[1];
    const int*   edge_idx = (const int*)  d_in[2];
    const float* values   = (const float*)d_in[3];
    const float* W        = (const float*)d_in[4];
    const float* att      = (const float*)d_in[5];
    float* out = (float*)d_out;

    // d_out layout: [x0h 25.6MB][m01h 25.6MB]. x0h dead after k2 -> its region
    // holds the 12.8MB rec array. m01h dead after k_bgather. k4 writes out last.
    _Float16* x0h_s  = (_Float16*)d_out;
    _Float16* m01h_s = x0h_s + (size_t)N_NODES * C;
    int2* rec = (int2*)d_out;                                  // 12.8 MB over x0h

    char*  p   = (char*)d_ws;
    _Float16* yh    = (_Float16*)p; p += (size_t)N_NODES * C * sizeof(_Float16); // 25.6 MB
    float* t_node   = (float*)p;  p += N_NODES * sizeof(float);
    float* s_edge   = (float*)p;  p += N_EDGES * sizeof(float);
    int*   btot     = (int*)p;    p += 512 * sizeof(int);
    int*   bbase    = (int*)p;    p += 512 * sizeof(int);
    int*   bcur     = (int*)p;    p += 512 * sizeof(int);
    int*   row_start= (int*)p;    p += (N_EDGES + 1) * sizeof(int);
    _Float16* wt    = (_Float16*)p; p += (size_t)C * C * sizeof(_Float16);       // 32 KB

    hipMemsetAsync(btot, 0, NB * sizeof(int), stream);

    k1_node_dot<<<N_NODES / 4, 256, 0, stream>>>(x0, att, t_node, x0h_s);
    k_rowptr<<<(NNZT + 255) / 256, 256, 0, stream>>>(edge_idx, row_start);
    k_wcvt  <<<(C * C + 255) / 256, 256, 0, stream>>>(W, wt);
    k2_edge_msg<<<N_EDGES / 4, 256, 0, stream>>>((const half8*)x0h_s, node_idx, row_start,
                                                 values, att, m01h_s, s_edge);

    k_bhist<<<256, 256, 0, stream>>>(node_idx, btot);
    k_bscan<<<1, 512, 0, stream>>>(btot, bbase, bcur);
    k_part <<<(NNZT + CHUNK - 1) / CHUNK, 512, 0, stream>>>(node_idx, edge_idx, values,
                                                            s_edge, t_node, bcur, rec);
    k_bgather<<<NB, 512, 0, stream>>>(rec, bbase, (const half8*)m01h_s, yh);
    k4_mfma<<<N_NODES / 16, 64, 0, stream>>>(yh, wt, out);
}

// Round 5
// 336.218 us; speedup vs baseline: 1.3235x; 1.0657x over previous
//
#include <hip/hip_runtime.h>
#include <math.h>

#define N_NODES 100000
#define N_EDGES 100000
#define NNZT    1600000
#define C       128
#define NB      ((N_NODES + 255) >> 8)    // 391 node-buckets of 256 nodes
#define CHUNK   4096                      // edges per k_part block
#define SPLIT   4                         // blocks per bucket in k_bgather
#define LCAP    2048                      // staged records per split block (mean 1024, sigma 32)

typedef _Float16 half8 __attribute__((ext_vector_type(8)));
typedef _Float16 h2    __attribute__((ext_vector_type(2)));
typedef float    f32x4 __attribute__((ext_vector_type(4)));

// K1: t_node[i] = dot(x_0[i], a_tgt); also emit x0h = (fp16)x0.
__global__ __launch_bounds__(256) void k1_node_dot(
    const float* __restrict__ x0, const float* __restrict__ att,
    float* __restrict__ t_node, _Float16* __restrict__ x0h)
{
    int wave = threadIdx.x >> 6;
    int lane = threadIdx.x & 63;
    int node = blockIdx.x * 4 + wave;          // 100000 % 4 == 0
    const float2 xv = *reinterpret_cast<const float2*>(x0 + (size_t)node * C + lane * 2);
    h2 hx = { (_Float16)xv.x, (_Float16)xv.y };
    *reinterpret_cast<h2*>(x0h + (size_t)node * C + lane * 2) = hx;
    const float2 av = *reinterpret_cast<const float2*>(att + C + lane * 2);
    float v = xv.x * av.x + xv.y * av.y;
    #pragma unroll
    for (int off = 32; off > 0; off >>= 1) v += __shfl_xor(v, off, 64);
    if (lane == 0) t_node[node] = v;
}

// RP: edge row pointer from sorted edge_idx, atomic-free one pass.
__global__ __launch_bounds__(256) void k_rowptr(
    const int* __restrict__ edge_idx, int* __restrict__ row_start)
{
    int e = blockIdx.x * 256 + threadIdx.x;
    if (e >= NNZT) return;
    int j = edge_idx[e];
    int jprev = (e == 0) ? -1 : edge_idx[e - 1];
    for (int k = jprev + 1; k <= j; ++k) row_start[k] = e;
    if (e == NNZT - 1)
        for (int k = j + 1; k <= N_EDGES; ++k) row_start[k] = NNZT;
}

// WC: Wt[n][k] = (fp16) W[k][n]  (transposed fp16 weight for MFMA B-frags)
__global__ __launch_bounds__(256) void k_wcvt(
    const float* __restrict__ W, _Float16* __restrict__ wt)
{
    int i = blockIdx.x * 256 + threadIdx.x;   // 16384
    int k = i >> 7, n = i & 127;
    wt[(size_t)n * C + k] = (_Float16)W[(size_t)k * C + n];
}

// K2: segment sum -> m01h row (fp16) + s_edge dot, via row_start.
// ONE WAVE PER ROW: 4 edge-slots x 16 lanes x half8, 4-wide MLP unroll.
// NO nontemporal hints (node_idx/values re-read by later kernels; round-2
// showed NT poisons that L2 reuse).
__global__ __launch_bounds__(256) void k2_edge_msg(
    const half8* __restrict__ x0h,
    const int*   __restrict__ node_idx,
    const int*   __restrict__ row_start,
    const float* __restrict__ values,
    const float* __restrict__ att,
    _Float16* __restrict__ m01h,
    float* __restrict__ s_edge)
{
    int wave = threadIdx.x >> 6;
    int lane = threadIdx.x & 63;
    int j    = blockIdx.x * 4 + wave;          // 100000 % 4 == 0
    int sub  = lane >> 4;                      // 0..3 edge slot
    int ln   = lane & 15;                      // half8 chunk of the row
    int start = row_start[j];
    int end   = row_start[j + 1];

    h2 hacc[4];
    #pragma unroll
    for (int q = 0; q < 4; ++q) hacc[q] = (h2){(_Float16)0.f, (_Float16)0.f};

    int e = start + sub;
    for (; e + 12 < end; e += 16) {
        int n0 = node_idx[e];
        int n1 = node_idx[e + 4];
        int n2 = node_idx[e + 8];
        int n3 = node_idx[e + 12];
        float f0 = values[e];
        float f1 = values[e + 4];
        float f2 = values[e + 8];
        float f3 = values[e + 12];
        half8 A  = x0h[(size_t)n0 * 16 + ln];
        half8 B  = x0h[(size_t)n1 * 16 + ln];
        half8 Cg = x0h[(size_t)n2 * 16 + ln];
        half8 D  = x0h[(size_t)n3 * 16 + ln];
        _Float16 v0 = (_Float16)f0, v1 = (_Float16)f1;
        _Float16 v2 = (_Float16)f2, v3 = (_Float16)f3;
        h2 v0p = {v0, v0}, v1p = {v1, v1}, v2p = {v2, v2}, v3p = {v3, v3};
        const h2* a2 = reinterpret_cast<const h2*>(&A);
        const h2* b2 = reinterpret_cast<const h2*>(&B);
        const h2* c2 = reinterpret_cast<const h2*>(&Cg);
        const h2* d2 = reinterpret_cast<const h2*>(&D);
        #pragma unroll
        for (int q = 0; q < 4; ++q)
            hacc[q] = a2[q] * v0p
                    + (b2[q] * v1p + (c2[q] * v2p + (d2[q] * v3p + hacc[q])));
    }
    for (; e + 4 < end; e += 8) {
        int n0 = node_idx[e];
        int n1 = node_idx[e + 4];
        _Float16 v0 = (_Float16)values[e];
        _Float16 v1 = (_Float16)values[e + 4];
        h2 v0p = {v0, v0}, v1p = {v1, v1};
        half8 A = x0h[(size_t)n0 * 16 + ln];
        half8 B = x0h[(size_t)n1 * 16 + ln];
        const h2* a2 = reinterpret_cast<const h2*>(&A);
        const h2* b2 = reinterpret_cast<const h2*>(&B);
        #pragma unroll
        for (int q = 0; q < 4; ++q)
            hacc[q] = a2[q] * v0p + (b2[q] * v1p + hacc[q]);
    }
    if (e < end) {
        int n0 = node_idx[e];
        _Float16 v0 = (_Float16)values[e];
        h2 v0p = {v0, v0};
        half8 A = x0h[(size_t)n0 * 16 + ln];
        const h2* a2 = reinterpret_cast<const h2*>(&A);
        #pragma unroll
        for (int q = 0; q < 4; ++q) hacc[q] = a2[q] * v0p + hacc[q];
    }

    // f32 cross-slot reduction, all in-wave.
    float f[8];
    #pragma unroll
    for (int q = 0; q < 4; ++q) {
        f[2 * q]     = (float)hacc[q][0];
        f[2 * q + 1] = (float)hacc[q][1];
    }
    #pragma unroll
    for (int q = 0; q < 8; ++q) {
        f[q] += __shfl_xor(f[q], 16, 64);
        f[q] += __shfl_xor(f[q], 32, 64);
    }
    if (lane < 16) {
        half8 hv;
        #pragma unroll
        for (int q = 0; q < 8; ++q) hv[q] = (_Float16)f[q];
        reinterpret_cast<half8*>(m01h + (size_t)j * C)[ln] = hv;
    }
    // s_edge[j] = dot(m01 row, a_src)
    f32x4 a0 = *reinterpret_cast<const f32x4*>(att + ln * 8);
    f32x4 a1 = *reinterpret_cast<const f32x4*>(att + ln * 8 + 4);
    float p = f[0] * a0[0] + f[1] * a0[1] + f[2] * a0[2] + f[3] * a0[3]
            + f[4] * a1[0] + f[5] * a1[1] + f[6] * a1[2] + f[7] * a1[3];
    #pragma unroll
    for (int off = 8; off > 0; off >>= 1) p += __shfl_xor(p, off, 64);
    if (lane == 0) s_edge[j] = p;
}

// BH: per-bucket totals. Wave-private LDS histograms -> ~100k global adds.
__global__ __launch_bounds__(256) void k_bhist(
    const int* __restrict__ node_idx, int* __restrict__ btot)
{
    __shared__ int cnt4[4][NB];
    int tid = threadIdx.x;
    int w   = tid >> 6;
    for (int b = tid; b < 4 * NB; b += 256) (&cnt4[0][0])[b] = 0;
    __syncthreads();
    const int per = (NNZT + 255) / 256;   // 6250
    int e0 = blockIdx.x * per;
    int e1 = e0 + per; if (e1 > NNZT) e1 = NNZT;
    for (int e = e0 + tid; e < e1; e += 256)
        atomicAdd(&cnt4[w][node_idx[e] >> 8], 1);
    __syncthreads();
    for (int b = tid; b < NB; b += 256) {
        int cc = cnt4[0][b] + cnt4[1][b] + cnt4[2][b] + cnt4[3][b];
        if (cc) atomicAdd(&btot[b], cc);
    }
}

// BS: exclusive scan of 391 bucket totals -> bbase[0..NB], bcur init.
__global__ __launch_bounds__(512) void k_bscan(
    const int* __restrict__ btot, int* __restrict__ bbase, int* __restrict__ bcur)
{
    __shared__ int s[512];
    int tid = threadIdx.x;
    int v = (tid < NB) ? btot[tid] : 0;
    s[tid] = v;
    __syncthreads();
    for (int off = 1; off < 512; off <<= 1) {
        int t = (tid >= off) ? s[tid - off] : 0;
        __syncthreads();
        s[tid] += t;
        __syncthreads();
    }
    if (tid < NB) { bbase[tid] = s[tid] - v; bcur[tid] = s[tid] - v; }
    if (tid == NB - 1) bbase[NB] = s[tid];
}

// PART: LDS counting-sort partition (temporal-density writes; verified
// round 4: write amplification ~1x). Record: {(n&255)<<17 | j, coef}.
__global__ __launch_bounds__(512) void k_part(
    const int*   __restrict__ node_idx,
    const int*   __restrict__ edge_idx,
    const float* __restrict__ values,
    const float* __restrict__ s_edge,
    const float* __restrict__ t_node,
    int*  __restrict__ bcur,
    int2* __restrict__ rec)
{
    __shared__ int hist[NB];
    __shared__ int lbase[NB];
    __shared__ int gb[NB];
    __shared__ int cur[NB];
    __shared__ int2 lrec[CHUNK];                  // 32 KB
    __shared__ unsigned short lbid[CHUNK];        // 8 KB
    int tid = threadIdx.x;
    int e0 = blockIdx.x * CHUNK;
    int m = NNZT - e0; if (m > CHUNK) m = CHUNK;

    for (int b = tid; b < NB; b += 512) hist[b] = 0;
    __syncthreads();
    for (int i = tid; i < m; i += 512)
        atomicAdd(&hist[node_idx[e0 + i] >> 8], 1);
    __syncthreads();
    int c = (tid < NB) ? hist[tid] : 0;
    for (int off = 1; off < NB; off <<= 1) {
        int t = 0;
        if (tid < NB && tid >= off) t = hist[tid - off];
        __syncthreads();
        if (tid < NB) hist[tid] += t;
        __syncthreads();
    }
    if (tid < NB) {
        int excl = hist[tid] - c;
        lbase[tid] = excl;
        cur[tid]   = excl;
        gb[tid]    = c ? atomicAdd(&bcur[tid], c) : 0;
    }
    __syncthreads();
    for (int i = tid; i < m; i += 512) {
        int e = e0 + i;
        int n = node_idx[e];
        int b = n >> 8;
        int j = edge_idx[e];
        float v = values[e];
        float s = s_edge[j] + t_node[n];
        float coef = (s > 0.f ? s : expm1f(s)) * v;
        int slot = atomicAdd(&cur[b], 1);
        lrec[slot] = make_int2(((n & 255) << 17) | j, __float_as_int(coef));
        lbid[slot] = (unsigned short)b;
    }
    __syncthreads();
    for (int s = tid; s < m; s += 512) {
        int b = lbid[s];
        rec[gb[b] + (s - lbase[b])] = lrec[s];
    }
}

// BG: fused sort+gather, SPLIT blocks per bucket for occupancy.
// Each block owns 64 locals: stages its ~1K records into LDS in node-sorted
// order (single global stream left in the gather loop), then wave-per-node
// gather from m01h with 4-wide MLP.
__global__ __launch_bounds__(256) void k_bgather(
    const int2*  __restrict__ rec,
    const int*   __restrict__ bbase,
    const half8* __restrict__ m01h,
    _Float16* __restrict__ yh)
{
    __shared__ int cnt[64], bl[64], cur[64];
    __shared__ int2 lrec[LCAP];       // 16 KB, node-sorted records
    __shared__ int ovf;
    int bid  = blockIdx.x;
    int b    = bid >> 2;              // bucket
    int part = bid & 3;
    int tid  = threadIdx.x;
    int lo = bbase[b], hi = bbase[b + 1];
    int m  = hi - lo;
    int l0 = part << 6;               // first local node of this part

    if (tid < 64) cnt[tid] = 0;
    if (tid == 0) ovf = 0;
    __syncthreads();
    // pass 1: count records in our 64-local window (slab read is sequential)
    for (int i = tid; i < m; i += 256) {
        int d = (int)(((unsigned)rec[lo + i].x) >> 17) - l0;
        if ((unsigned)d < 64u) atomicAdd(&cnt[d], 1);
    }
    __syncthreads();
    if (tid < 64) bl[tid] = cnt[tid];
    __syncthreads();
    for (int off = 1; off < 64; off <<= 1) {
        int t = 0;
        if (tid < 64 && tid >= off) t = bl[tid - off];
        __syncthreads();
        if (tid < 64) bl[tid] += t;
        __syncthreads();
    }
    if (tid < 64) cur[tid] = bl[tid] - cnt[tid];
    if (tid == 63 && bl[63] > LCAP) ovf = 1;
    __syncthreads();
    if (!ovf) {
        // pass 2: stage matching records node-sorted into LDS
        for (int i = tid; i < m; i += 256) {
            int2 r = rec[lo + i];
            int d = (int)(((unsigned)r.x) >> 17) - l0;
            if ((unsigned)d < 64u) {
                int p = atomicAdd(&cur[d], 1);
                lrec[p] = r;
            }
        }
    }
    __syncthreads();

    int wave = tid >> 6, lane = tid & 63, sub = lane >> 4, ln = lane & 15;
    for (int d = wave; d < 64; d += 4) {
        int n = (b << 8) + l0 + d;
        if (n >= N_NODES) break;
        int cb = bl[d] - cnt[d];
        int cc = cnt[d];
        float facc[8];
        #pragma unroll
        for (int q = 0; q < 8; ++q) facc[q] = 0.f;
        if (!ovf) {
            int i = sub;
            for (; i + 12 < cc; i += 16) {           // 4-wide MLP
                int2 r0 = lrec[cb + i];
                int2 r1 = lrec[cb + i + 4];
                int2 r2 = lrec[cb + i + 8];
                int2 r3 = lrec[cb + i + 12];
                half8 a0 = m01h[(size_t)(r0.x & 0x1FFFF) * 16 + ln];
                half8 a1 = m01h[(size_t)(r1.x & 0x1FFFF) * 16 + ln];
                half8 a2 = m01h[(size_t)(r2.x & 0x1FFFF) * 16 + ln];
                half8 a3 = m01h[(size_t)(r3.x & 0x1FFFF) * 16 + ln];
                float c0 = __int_as_float(r0.y);
                float c1 = __int_as_float(r1.y);
                float c2 = __int_as_float(r2.y);
                float c3 = __int_as_float(r3.y);
                #pragma unroll
                for (int q = 0; q < 8; ++q)
                    facc[q] += c0 * (float)a0[q] + c1 * (float)a1[q]
                             + c2 * (float)a2[q] + c3 * (float)a3[q];
            }
            for (; i + 4 < cc; i += 8) {             // 2-wide tail
                int2 r0 = lrec[cb + i];
                int2 r1 = lrec[cb + i + 4];
                half8 a0 = m01h[(size_t)(r0.x & 0x1FFFF) * 16 + ln];
                half8 a1 = m01h[(size_t)(r1.x & 0x1FFFF) * 16 + ln];
                float c0 = __int_as_float(r0.y);
                float c1 = __int_as_float(r1.y);
                #pragma unroll
                for (int q = 0; q < 8; ++q)
                    facc[q] += c0 * (float)a0[q] + c1 * (float)a1[q];
            }
            if (i < cc) {                            // 1-wide tail
                int2 r0 = lrec[cb + i];
                half8 a0 = m01h[(size_t)(r0.x & 0x1FFFF) * 16 + ln];
                float c0 = __int_as_float(r0.y);
                #pragma unroll
                for (int q = 0; q < 8; ++q) facc[q] += c0 * (float)a0[q];
            }
        } else {
            // insurance fallback (never taken for this data): scan slab
            for (int x = sub; x < m; x += 4) {
                int2 r = rec[lo + x];
                if ((int)(((unsigned)r.x) >> 17) == l0 + d) {
                    float c0 = __int_as_float(r.y);
                    half8 a0 = m01h[(size_t)(r.x & 0x1FFFF) * 16 + ln];
                    #pragma unroll
                    for (int q = 0; q < 8; ++q) facc[q] += c0 * (float)a0[q];
                }
            }
        }
        #pragma unroll
        for (int q = 0; q < 8; ++q) {
            facc[q] += __shfl_xor(facc[q], 16, 64);
            facc[q] += __shfl_xor(facc[q], 32, 64);
        }
        if (lane < 16) {
            half8 hv;
            #pragma unroll
            for (int q = 0; q < 8; ++q) hv[q] = (_Float16)facc[q];
            reinterpret_cast<half8*>(yh + (size_t)n * C)[ln] = hv;
        }
    }
}

// K4: out = yh @ W via MFMA f16. One wave per 16 rows; 8 col-tiles x 4 k-chunks.
__global__ __launch_bounds__(64) void k4_mfma(
    const _Float16* __restrict__ yh,   // N_NODES x C row-major
    const _Float16* __restrict__ wt,   // wt[n*C+k] = W[k][n]
    float* __restrict__ out)
{
    int lane = threadIdx.x;            // 0..63
    int m    = lane & 15;
    int quad = lane >> 4;              // 0..3
    int rb   = blockIdx.x * 16;
    const _Float16* yrow = yh + (size_t)(rb + m) * C + quad * 8;
    half8 a[4];
    #pragma unroll
    for (int kc = 0; kc < 4; ++kc)
        a[kc] = *reinterpret_cast<const half8*>(yrow + kc * 32);
    #pragma unroll
    for (int ct = 0; ct < 8; ++ct) {
        const _Float16* wrow = wt + (size_t)(ct * 16 + m) * C + quad * 8;
        f32x4 acc = {0.f, 0.f, 0.f, 0.f};
        #pragma unroll
        for (int kc = 0; kc < 4; ++kc) {
            half8 b = *reinterpret_cast<const half8*>(wrow + kc * 32);
            acc = __builtin_amdgcn_mfma_f32_16x16x32_f16(a[kc], b, acc, 0, 0, 0);
        }
        int orow = rb + quad * 4;
        int ocol = ct * 16 + m;
        #pragma unroll
        for (int r = 0; r < 4; ++r)
            out[(size_t)(orow + r) * C + ocol] = acc[r];
    }
}

extern "C" void kernel_launch(void* const* d_in, const int* in_sizes, int n_in,
                              void* d_out, int out_size, void* d_ws, size_t ws_size,
                              hipStream_t stream)
{
    const float* x0       = (const float*)d_in[0];
    const int*   node_idx = (const int*)  d_in[1];
    const int*   edge_idx = (const int*)  d_in[2];
    const float* values   = (const float*)d_in[3];
    const float* W        = (const float*)d_in[4];
    const float* att      = (const float*)d_in[5];
    float* out = (float*)d_out;

    // d_out layout: [x0h 25.6MB][m01h 25.6MB]. x0h dead after k2 -> its region
    // holds the 12.8MB rec array. m01h dead after k_bgather. k4 writes out last.
    _Float16* x0h_s  = (_Float16*)d_out;
    _Float16* m01h_s = x0h_s + (size_t)N_NODES * C;
    int2* rec = (int2*)d_out;                                  // 12.8 MB over x0h

    char*  p   = (char*)d_ws;
    _Float16* yh    = (_Float16*)p; p += (size_t)N_NODES * C * sizeof(_Float16); // 25.6 MB
    float* t_node   = (float*)p;  p += N_NODES * sizeof(float);
    float* s_edge   = (float*)p;  p += N_EDGES * sizeof(float);
    int*   btot     = (int*)p;    p += 512 * sizeof(int);
    int*   bbase    = (int*)p;    p += 512 * sizeof(int);
    int*   bcur     = (int*)p;    p += 512 * sizeof(int);
    int*   row_start= (int*)p;    p += (N_EDGES + 1) * sizeof(int);
    _Float16* wt    = (_Float16*)p; p += (size_t)C * C * sizeof(_Float16);       // 32 KB

    hipMemsetAsync(btot, 0, NB * sizeof(int), stream);

    k1_node_dot<<<N_NODES / 4, 256, 0, stream>>>(x0, att, t_node, x0h_s);
    k_rowptr<<<(NNZT + 255) / 256, 256, 0, stream>>>(edge_idx, row_start);
    k_wcvt  <<<(C * C + 255) / 256, 256, 0, stream>>>(W, wt);
    k2_edge_msg<<<N_EDGES / 4, 256, 0, stream>>>((const half8*)x0h_s, node_idx, row_start,
                                                 values, att, m01h_s, s_edge);

    k_bhist<<<256, 256, 0, stream>>>(node_idx, btot);
    k_bscan<<<1, 512, 0, stream>>>(btot, bbase, bcur);
    k_part <<<(NNZT + CHUNK - 1) / CHUNK, 512, 0, stream>>>(node_idx, edge_idx, values,
                                                            s_edge, t_node, bcur, rec);
    k_bgather<<<NB * SPLIT, 256, 0, stream>>>(rec, bbase, (const half8*)m01h_s, yh);
    k4_mfma<<<N_NODES / 16, 64, 0, stream>>>(yh, wt, out);
}

// Round 6
// 323.846 us; speedup vs baseline: 1.3740x; 1.0382x over previous
//
#include <hip/hip_runtime.h>
#include <math.h>

#define N_NODES 100000
#define N_EDGES 100000
#define NNZT    1600000
#define C       128
#define NB      ((N_NODES + 255) >> 8)    // 391 node-buckets of 256 nodes
#define CHUNK   4096                      // edges per k_part block
#define SCAP    5120                      // k_bsort slab capacity (mean 4092, sigma~64)

typedef _Float16 half8 __attribute__((ext_vector_type(8)));
typedef _Float16 h2    __attribute__((ext_vector_type(2)));
typedef float    f32x4 __attribute__((ext_vector_type(4)));

// K1: t_node[i] = dot(x_0[i], a_tgt); also emit x0h = (fp16)x0.
__global__ __launch_bounds__(256) void k1_node_dot(
    const float* __restrict__ x0, const float* __restrict__ att,
    float* __restrict__ t_node, _Float16* __restrict__ x0h)
{
    int wave = threadIdx.x >> 6;
    int lane = threadIdx.x & 63;
    int node = blockIdx.x * 4 + wave;          // 100000 % 4 == 0
    const float2 xv = *reinterpret_cast<const float2*>(x0 + (size_t)node * C + lane * 2);
    h2 hx = { (_Float16)xv.x, (_Float16)xv.y };
    *reinterpret_cast<h2*>(x0h + (size_t)node * C + lane * 2) = hx;
    const float2 av = *reinterpret_cast<const float2*>(att + C + lane * 2);
    float v = xv.x * av.x + xv.y * av.y;
    #pragma unroll
    for (int off = 32; off > 0; off >>= 1) v += __shfl_xor(v, off, 64);
    if (lane == 0) t_node[node] = v;
}

// RP: edge row pointer from sorted edge_idx, atomic-free one pass.
__global__ __launch_bounds__(256) void k_rowptr(
    const int* __restrict__ edge_idx, int* __restrict__ row_start)
{
    int e = blockIdx.x * 256 + threadIdx.x;
    if (e >= NNZT) return;
    int j = edge_idx[e];
    int jprev = (e == 0) ? -1 : edge_idx[e - 1];
    for (int k = jprev + 1; k <= j; ++k) row_start[k] = e;
    if (e == NNZT - 1)
        for (int k = j + 1; k <= N_EDGES; ++k) row_start[k] = NNZT;
}

// WC: Wt[n][k] = (fp16) W[k][n]  (transposed fp16 weight for MFMA B-frags)
__global__ __launch_bounds__(256) void k_wcvt(
    const float* __restrict__ W, _Float16* __restrict__ wt)
{
    int i = blockIdx.x * 256 + threadIdx.x;   // 16384
    int k = i >> 7, n = i & 127;
    wt[(size_t)n * C + k] = (_Float16)W[(size_t)k * C + n];
}

// K2: segment sum -> m01h row (fp16) + s_edge dot, via row_start.
// ONE WAVE PER ROW: 4 edge-slots x 16 lanes x half8, 4-wide MLP unroll.
// No NT hints (round-2: NT on shared streams poisons later kernels' L2 reuse).
__global__ __launch_bounds__(256) void k2_edge_msg(
    const half8* __restrict__ x0h,
    const int*   __restrict__ node_idx,
    const int*   __restrict__ row_start,
    const float* __restrict__ values,
    const float* __restrict__ att,
    _Float16* __restrict__ m01h,
    float* __restrict__ s_edge)
{
    int wave = threadIdx.x >> 6;
    int lane = threadIdx.x & 63;
    int j    = blockIdx.x * 4 + wave;          // 100000 % 4 == 0
    int sub  = lane >> 4;                      // 0..3 edge slot
    int ln   = lane & 15;                      // half8 chunk of the row
    int start = row_start[j];
    int end   = row_start[j + 1];

    h2 hacc[4];
    #pragma unroll
    for (int q = 0; q < 4; ++q) hacc[q] = (h2){(_Float16)0.f, (_Float16)0.f};

    int e = start + sub;
    for (; e + 12 < end; e += 16) {
        int n0 = node_idx[e];
        int n1 = node_idx[e + 4];
        int n2 = node_idx[e + 8];
        int n3 = node_idx[e + 12];
        float f0 = values[e];
        float f1 = values[e + 4];
        float f2 = values[e + 8];
        float f3 = values[e + 12];
        half8 A  = x0h[(size_t)n0 * 16 + ln];
        half8 B  = x0h[(size_t)n1 * 16 + ln];
        half8 Cg = x0h[(size_t)n2 * 16 + ln];
        half8 D  = x0h[(size_t)n3 * 16 + ln];
        _Float16 v0 = (_Float16)f0, v1 = (_Float16)f1;
        _Float16 v2 = (_Float16)f2, v3 = (_Float16)f3;
        h2 v0p = {v0, v0}, v1p = {v1, v1}, v2p = {v2, v2}, v3p = {v3, v3};
        const h2* a2 = reinterpret_cast<const h2*>(&A);
        const h2* b2 = reinterpret_cast<const h2*>(&B);
        const h2* c2 = reinterpret_cast<const h2*>(&Cg);
        const h2* d2 = reinterpret_cast<const h2*>(&D);
        #pragma unroll
        for (int q = 0; q < 4; ++q)
            hacc[q] = a2[q] * v0p
                    + (b2[q] * v1p + (c2[q] * v2p + (d2[q] * v3p + hacc[q])));
    }
    for (; e + 4 < end; e += 8) {
        int n0 = node_idx[e];
        int n1 = node_idx[e + 4];
        _Float16 v0 = (_Float16)values[e];
        _Float16 v1 = (_Float16)values[e + 4];
        h2 v0p = {v0, v0}, v1p = {v1, v1};
        half8 A = x0h[(size_t)n0 * 16 + ln];
        half8 B = x0h[(size_t)n1 * 16 + ln];
        const h2* a2 = reinterpret_cast<const h2*>(&A);
        const h2* b2 = reinterpret_cast<const h2*>(&B);
        #pragma unroll
        for (int q = 0; q < 4; ++q)
            hacc[q] = a2[q] * v0p + (b2[q] * v1p + hacc[q]);
    }
    if (e < end) {
        int n0 = node_idx[e];
        _Float16 v0 = (_Float16)values[e];
        h2 v0p = {v0, v0};
        half8 A = x0h[(size_t)n0 * 16 + ln];
        const h2* a2 = reinterpret_cast<const h2*>(&A);
        #pragma unroll
        for (int q = 0; q < 4; ++q) hacc[q] = a2[q] * v0p + hacc[q];
    }

    float f[8];
    #pragma unroll
    for (int q = 0; q < 4; ++q) {
        f[2 * q]     = (float)hacc[q][0];
        f[2 * q + 1] = (float)hacc[q][1];
    }
    #pragma unroll
    for (int q = 0; q < 8; ++q) {
        f[q] += __shfl_xor(f[q], 16, 64);
        f[q] += __shfl_xor(f[q], 32, 64);
    }
    if (lane < 16) {
        half8 hv;
        #pragma unroll
        for (int q = 0; q < 8; ++q) hv[q] = (_Float16)f[q];
        reinterpret_cast<half8*>(m01h + (size_t)j * C)[ln] = hv;
    }
    f32x4 a0 = *reinterpret_cast<const f32x4*>(att + ln * 8);
    f32x4 a1 = *reinterpret_cast<const f32x4*>(att + ln * 8 + 4);
    float p = f[0] * a0[0] + f[1] * a0[1] + f[2] * a0[2] + f[3] * a0[3]
            + f[4] * a1[0] + f[5] * a1[1] + f[6] * a1[2] + f[7] * a1[3];
    #pragma unroll
    for (int off = 8; off > 0; off >>= 1) p += __shfl_xor(p, off, 64);
    if (lane == 0) s_edge[j] = p;
}

// BH: per-bucket totals. Wave-private LDS histograms -> ~100k global adds.
__global__ __launch_bounds__(256) void k_bhist(
    const int* __restrict__ node_idx, int* __restrict__ btot)
{
    __shared__ int cnt4[4][NB];
    int tid = threadIdx.x;
    int w   = tid >> 6;
    for (int b = tid; b < 4 * NB; b += 256) (&cnt4[0][0])[b] = 0;
    __syncthreads();
    const int per = (NNZT + 255) / 256;   // 6250
    int e0 = blockIdx.x * per;
    int e1 = e0 + per; if (e1 > NNZT) e1 = NNZT;
    for (int e = e0 + tid; e < e1; e += 256)
        atomicAdd(&cnt4[w][node_idx[e] >> 8], 1);
    __syncthreads();
    for (int b = tid; b < NB; b += 256) {
        int cc = cnt4[0][b] + cnt4[1][b] + cnt4[2][b] + cnt4[3][b];
        if (cc) atomicAdd(&btot[b], cc);
    }
}

// BS: exclusive scan of 391 bucket totals -> bbase[0..NB], bcur init.
__global__ __launch_bounds__(512) void k_bscan(
    const int* __restrict__ btot, int* __restrict__ bbase, int* __restrict__ bcur)
{
    __shared__ int s[512];
    int tid = threadIdx.x;
    int v = (tid < NB) ? btot[tid] : 0;
    s[tid] = v;
    __syncthreads();
    for (int off = 1; off < 512; off <<= 1) {
        int t = (tid >= off) ? s[tid - off] : 0;
        __syncthreads();
        s[tid] += t;
        __syncthreads();
    }
    if (tid < NB) { bbase[tid] = s[tid] - v; bcur[tid] = s[tid] - v; }
    if (tid == NB - 1) bbase[NB] = s[tid];
}

// PART: LDS counting-sort partition (temporal-density writes; verified
// round 4: write amplification ~1x). Record: {(n&255)<<17 | j, coef}.
__global__ __launch_bounds__(512) void k_part(
    const int*   __restrict__ node_idx,
    const int*   __restrict__ edge_idx,
    const float* __restrict__ values,
    const float* __restrict__ s_edge,
    const float* __restrict__ t_node,
    int*  __restrict__ bcur,
    int2* __restrict__ rec)
{
    __shared__ int hist[NB];
    __shared__ int lbase[NB];
    __shared__ int gb[NB];
    __shared__ int cur[NB];
    __shared__ int2 lrec[CHUNK];                  // 32 KB
    __shared__ unsigned short lbid[CHUNK];        // 8 KB
    int tid = threadIdx.x;
    int e0 = blockIdx.x * CHUNK;
    int m = NNZT - e0; if (m > CHUNK) m = CHUNK;

    for (int b = tid; b < NB; b += 512) hist[b] = 0;
    __syncthreads();
    for (int i = tid; i < m; i += 512)
        atomicAdd(&hist[node_idx[e0 + i] >> 8], 1);
    __syncthreads();
    int c = (tid < NB) ? hist[tid] : 0;
    for (int off = 1; off < NB; off <<= 1) {
        int t = 0;
        if (tid < NB && tid >= off) t = hist[tid - off];
        __syncthreads();
        if (tid < NB) hist[tid] += t;
        __syncthreads();
    }
    if (tid < NB) {
        int excl = hist[tid] - c;
        lbase[tid] = excl;
        cur[tid]   = excl;
        gb[tid]    = c ? atomicAdd(&bcur[tid], c) : 0;
    }
    __syncthreads();
    for (int i = tid; i < m; i += 512) {
        int e = e0 + i;
        int n = node_idx[e];
        int b = n >> 8;
        int j = edge_idx[e];
        float v = values[e];
        float s = s_edge[j] + t_node[n];
        float coef = (s > 0.f ? s : expm1f(s)) * v;
        int slot = atomicAdd(&cur[b], 1);
        lrec[slot] = make_int2(((n & 255) << 17) | j, __float_as_int(coef));
        lbid[slot] = (unsigned short)b;
    }
    __syncthreads();
    for (int s = tid; s < m; s += 512) {
        int b = lbid[s];
        rec[gb[b] + (s - lbase[b])] = lrec[s];
    }
}

// BSORT: one block per bucket. ONE sequential read of the slab into LDS,
// node-sort via 256-counter hist+scan+ord, ONE dense sequential write of the
// sorted slab (jc) + per-node base/count. Replaces round-5's 8 redundant
// slab passes (4 split-blocks x 2 passes) with exactly 2.
__global__ __launch_bounds__(512) void k_bsort(
    const int2* __restrict__ rec,
    const int*  __restrict__ bbase,
    int2* __restrict__ jc,
    int*  __restrict__ base,
    int*  __restrict__ count)
{
    __shared__ int cnt[256], bl[256], cur[256];
    __shared__ int2 lrec[SCAP];                // 40 KB
    __shared__ unsigned short ord[SCAP];       // 10 KB
    int b = blockIdx.x, tid = threadIdx.x;
    int lo = bbase[b], hi = bbase[b + 1];
    int m = hi - lo;
    bool ovf = (m > SCAP);   // never for this data (mean 4092, cap = +16 sigma)

    if (tid < 256) cnt[tid] = 0;
    __syncthreads();
    for (int i = tid; i < m; i += 512) {
        int2 r = rec[lo + i];
        if (i < SCAP) lrec[i] = r;
        atomicAdd(&cnt[((unsigned)r.x) >> 17], 1);
    }
    __syncthreads();
    if (tid < 256) bl[tid] = cnt[tid];
    __syncthreads();
    for (int off = 1; off < 256; off <<= 1) {
        int t = 0;
        if (tid < 256 && tid >= off) t = bl[tid - off];
        __syncthreads();
        if (tid < 256) bl[tid] += t;
        __syncthreads();
    }
    if (tid < 256) {
        int excl = bl[tid] - cnt[tid];
        cur[tid] = excl;
        int nn = (b << 8) + tid;
        if (nn < N_NODES) { base[nn] = lo + excl; count[nn] = cnt[tid]; }
    }
    __syncthreads();
    if (!ovf) {
        for (int i = tid; i < m; i += 512) {
            int local = ((unsigned)lrec[i].x) >> 17;
            int p = atomicAdd(&cur[local], 1);
            ord[p] = (unsigned short)i;
        }
        __syncthreads();
        for (int s = tid; s < m; s += 512)
            jc[lo + s] = lrec[ord[s]];
    } else {
        // correct-but-slow fallback: scattered (within-slab) direct writes
        for (int i = tid; i < m; i += 512) {
            int2 r = rec[lo + i];
            int local = ((unsigned)r.x) >> 17;
            int p = atomicAdd(&cur[local], 1);
            jc[lo + p] = r;
        }
    }
}

// K3M: fused gather + output GEMM. Full grid (6250 blocks), no sort work.
// Phase 1: wave-per-node (4 nodes/wave, 16/block), 4 slots x 16 lanes x half8,
// MLP-4 over the node's contiguous jc records; shfl reduce; row -> LDS tile.
// Phase 2: the 16x128 yh tile @ 128x128 W via MFMA (verified k4 layout),
// each wave owns 2 col-tiles. Deletes the 51MB yh round-trip + one launch.
__global__ __launch_bounds__(256) void k3m(
    const int2*  __restrict__ jc,
    const int*   __restrict__ base,
    const int*   __restrict__ count,
    const half8* __restrict__ m01h,
    const _Float16* __restrict__ wt,   // wt[n*C+k] = W[k][n]
    float* __restrict__ out)
{
    __shared__ _Float16 yt[16][136];   // row stride 272B: 16B-aligned, bank-spread
    int tid  = threadIdx.x;
    int wave = tid >> 6, lane = tid & 63, sub = lane >> 4, ln = lane & 15;
    int nb = blockIdx.x * 16;          // 100000 = 6250*16 exactly

    #pragma unroll
    for (int r = 0; r < 4; ++r) {
        int n  = nb + wave * 4 + r;
        int b  = base[n];
        int cc = count[n];
        float facc[8];
        #pragma unroll
        for (int q = 0; q < 8; ++q) facc[q] = 0.f;
        int i = sub;
        for (; i + 12 < cc; i += 16) {            // 4-wide MLP
            int2 r0 = jc[b + i];
            int2 r1 = jc[b + i + 4];
            int2 r2 = jc[b + i + 8];
            int2 r3 = jc[b + i + 12];
            half8 a0 = m01h[(size_t)(r0.x & 0x1FFFF) * 16 + ln];
            half8 a1 = m01h[(size_t)(r1.x & 0x1FFFF) * 16 + ln];
            half8 a2 = m01h[(size_t)(r2.x & 0x1FFFF) * 16 + ln];
            half8 a3 = m01h[(size_t)(r3.x & 0x1FFFF) * 16 + ln];
            float c0 = __int_as_float(r0.y);
            float c1 = __int_as_float(r1.y);
            float c2 = __int_as_float(r2.y);
            float c3 = __int_as_float(r3.y);
            #pragma unroll
            for (int q = 0; q < 8; ++q)
                facc[q] += c0 * (float)a0[q] + c1 * (float)a1[q]
                         + c2 * (float)a2[q] + c3 * (float)a3[q];
        }
        for (; i + 4 < cc; i += 8) {              // 2-wide tail
            int2 r0 = jc[b + i];
            int2 r1 = jc[b + i + 4];
            half8 a0 = m01h[(size_t)(r0.x & 0x1FFFF) * 16 + ln];
            half8 a1 = m01h[(size_t)(r1.x & 0x1FFFF) * 16 + ln];
            float c0 = __int_as_float(r0.y);
            float c1 = __int_as_float(r1.y);
            #pragma unroll
            for (int q = 0; q < 8; ++q)
                facc[q] += c0 * (float)a0[q] + c1 * (float)a1[q];
        }
        if (i < cc) {                             // 1-wide tail
            int2 r0 = jc[b + i];
            half8 a0 = m01h[(size_t)(r0.x & 0x1FFFF) * 16 + ln];
            float c0 = __int_as_float(r0.y);
            #pragma unroll
            for (int q = 0; q < 8; ++q) facc[q] += c0 * (float)a0[q];
        }
        #pragma unroll
        for (int q = 0; q < 8; ++q) {
            facc[q] += __shfl_xor(facc[q], 16, 64);
            facc[q] += __shfl_xor(facc[q], 32, 64);
        }
        if (lane < 16) {
            half8 hv;
            #pragma unroll
            for (int q = 0; q < 8; ++q) hv[q] = (_Float16)facc[q];
            *reinterpret_cast<half8*>(&yt[wave * 4 + r][ln * 8]) = hv;
        }
    }
    __syncthreads();

    // Phase 2: out tile = yt (16x128) @ W (128x128), k4's verified layout.
    int m    = lane & 15;
    int quad = lane >> 4;
    half8 a[4];
    #pragma unroll
    for (int kc = 0; kc < 4; ++kc)
        a[kc] = *reinterpret_cast<const half8*>(&yt[m][quad * 8 + kc * 32]);
    #pragma unroll
    for (int t = 0; t < 2; ++t) {
        int ct = wave * 2 + t;                    // waves cover col-tiles 0..7
        const _Float16* wrow = wt + (size_t)(ct * 16 + m) * C + quad * 8;
        f32x4 acc = {0.f, 0.f, 0.f, 0.f};
        #pragma unroll
        for (int kc = 0; kc < 4; ++kc) {
            half8 bfr = *reinterpret_cast<const half8*>(wrow + kc * 32);
            acc = __builtin_amdgcn_mfma_f32_16x16x32_f16(a[kc], bfr, acc, 0, 0, 0);
        }
        int orow = nb + quad * 4;
        int ocol = ct * 16 + m;
        #pragma unroll
        for (int r = 0; r < 4; ++r)
            out[(size_t)(orow + r) * C + ocol] = acc[r];
    }
}

extern "C" void kernel_launch(void* const* d_in, const int* in_sizes, int n_in,
                              void* d_out, int out_size, void* d_ws, size_t ws_size,
                              hipStream_t stream)
{
    const float* x0       = (const float*)d_in[0];
    const int*   node_idx = (const int*)  d_in[1];
    const int*   edge_idx = (const int*)  d_in[2];
    const float* values   = (const float*)d_in[3];
    const float* W        = (const float*)d_in[4];
    const float* att      = (const float*)d_in[5];
    float* out = (float*)d_out;

    // d_out: [x0h 25.6MB][spare]. x0h dead after k2 -> rec (12.8MB) overlays it;
    // rec dead after k_bsort. k3m writes out (51.2MB = all of d_out) last.
    // m01h must OUTLIVE rec/jc and stay live while out is written -> it lives
    // in ws, not d_out (k3m reads m01h while writing out).
    _Float16* x0h_s = (_Float16*)d_out;
    int2* rec = (int2*)d_out;                                  // 12.8 MB over x0h

    char*  p   = (char*)d_ws;
    _Float16* m01h_s = (_Float16*)p; p += (size_t)N_EDGES * C * sizeof(_Float16); // 25.6 MB
    int2*  jc       = (int2*)p;   p += (size_t)NNZT * sizeof(int2);               // 12.8 MB
    float* t_node   = (float*)p;  p += N_NODES * sizeof(float);
    float* s_edge   = (float*)p;  p += N_EDGES * sizeof(float);
    int*   base     = (int*)p;    p += N_NODES * sizeof(int);
    int*   count    = (int*)p;    p += N_NODES * sizeof(int);
    int*   btot     = (int*)p;    p += 512 * sizeof(int);
    int*   bbase    = (int*)p;    p += 512 * sizeof(int);
    int*   bcur     = (int*)p;    p += 512 * sizeof(int);
    int*   row_start= (int*)p;    p += (N_EDGES + 1) * sizeof(int);
    _Float16* wt    = (_Float16*)p; p += (size_t)C * C * sizeof(_Float16);        // 32 KB

    hipMemsetAsync(btot, 0, NB * sizeof(int), stream);

    k1_node_dot<<<N_NODES / 4, 256, 0, stream>>>(x0, att, t_node, x0h_s);
    k_rowptr<<<(NNZT + 255) / 256, 256, 0, stream>>>(edge_idx, row_start);
    k_wcvt  <<<(C * C + 255) / 256, 256, 0, stream>>>(W, wt);
    k2_edge_msg<<<N_EDGES / 4, 256, 0, stream>>>((const half8*)x0h_s, node_idx, row_start,
                                                 values, att, m01h_s, s_edge);

    k_bhist<<<256, 256, 0, stream>>>(node_idx, btot);
    k_bscan<<<1, 512, 0, stream>>>(btot, bbase, bcur);
    k_part <<<(NNZT + CHUNK - 1) / CHUNK, 512, 0, stream>>>(node_idx, edge_idx, values,
                                                            s_edge, t_node, bcur, rec);
    k_bsort<<<NB, 512, 0, stream>>>(rec, bbase, jc, base, count);
    k3m    <<<N_NODES / 16, 256, 0, stream>>>(jc, base, count, (const half8*)m01h_s,
                                              wt, out);
}